// Round 18
// baseline (90.822 us; speedup 1.0000x reference)
//
#include <hip/hip_runtime.h>
#include <hip/hip_bf16.h>
#include <stdint.h>
#include <math.h>

#define N_HEADS 16
#define HEAD_DIM 64
#define SEQ_LEN 2048
#define KVBLK 64                    // two verified 32-row sub-blocks per iter
#define NT 16                       // iterations per half-stream
#define NTILE_TOT (SEQ_LEN / 32)    // 32-row image tiles

typedef __bf16 bf16x8 __attribute__((ext_vector_type(8)));
typedef __bf16 bf16x4 __attribute__((ext_vector_type(4)));
typedef short  s16x4  __attribute__((ext_vector_type(4)));
typedef float  f32x4  __attribute__((ext_vector_type(4)));
typedef unsigned int u32x4 __attribute__((ext_vector_type(4)));

#if __has_builtin(__builtin_amdgcn_mfma_f32_16x16x16bf16_1k)
#define HAVE_MFMA16 1
#else
#define HAVE_MFMA16 0
#endif

#if __has_builtin(__builtin_amdgcn_global_load_lds)
#define HAVE_GLL 1
// DMA 16B/lane: LDS dest = wave-uniform base + lane*16 (HW adds lane offset);
// global source is per-lane (m97/m104/m173).
#define GLL16(gsrc, ldst)                                                     \
    __builtin_amdgcn_global_load_lds(                                         \
        (const __attribute__((address_space(1))) void*)(gsrc),                \
        (__attribute__((address_space(3))) void*)(ldst), 16, 0, 0)
#else
#define HAVE_GLL 0
#endif

static __device__ __forceinline__ unsigned pkbf(float a, float b) {
    union { __bf16 h[2]; unsigned u; } t;
    t.h[0] = (__bf16)a; t.h[1] = (__bf16)b;
    return t.u;
}

// Byte position of k (0..31) within a 64B Vt row.
// MFMA16: k-interleaved so chunk at g*16 = [jt=0,g,b0..3][jt=1,g,b0..3]
//         -> ONE ds_read_b128 feeds BOTH K=16 MFMAs of a sub-block (R16).
static __device__ __forceinline__ int vpos(int k) {
#if HAVE_MFMA16
    return ((k & 12) << 2) + ((k & 16) >> 1) + ((k & 3) << 1);
#else
    return k * 2;
#endif
}

// Prep: swizzled bf16 images of K (row-major) and Vt (transposed, k-interleaved
// rows), one 4 KB block per (head, 32-row tile) — byte-exact replicas of the
// LDS tiles. Also computes max ||K row||^2 per head (for the fixed softmax
// bound): 8-lane shfl row-reduce + one atomicMax(int-bits) per row.
//   K : row-major bf16 [32][64], addr = row*128 + (off ^ ((row&7)<<4))
//   Vt: bf16 [64 d-rows][32 k], byte = (vc*64 + vpos(k)) ^ ((vc&7)<<4)
__global__ __launch_bounds__(256)
void prep_kernel(const float* __restrict__ k,
                 const float* __restrict__ v,
                 char* __restrict__ kimg,
                 char* __restrict__ vtimg,
                 float* __restrict__ knorm) {
    const int ts  = blockIdx.x;         // 32-row tile 0..63
    const int h   = blockIdx.y;
    const int tid = threadIdx.x;
    const int s0  = ts * 32;
    const size_t blk = ((size_t)h * NTILE_TOT + ts) * 4096;

    const int krow = tid >> 3;
    const int kcol = (tid & 7) * 8;
    const float* ks = k + ((size_t)h * SEQ_LEN + s0 + krow) * HEAD_DIM + kcol;
    f32x4 a = *(const f32x4*)ks;
    f32x4 b = *(const f32x4*)(ks + 4);
    bf16x8 kb;
    float pn = 0.0f;
    #pragma unroll
    for (int i = 0; i < 4; ++i) {
        kb[i] = (__bf16)a[i]; kb[4 + i] = (__bf16)b[i];
        pn += a[i] * a[i] + b[i] * b[i];
    }
    *(bf16x8*)(kimg + blk + krow * 128 + ((kcol * 2) ^ ((krow & 7) << 4))) = kb;

    // per-row ||K||^2 -> per-head max (positive floats: int-bits monotonic)
    pn += __shfl_xor(pn, 1);
    pn += __shfl_xor(pn, 2);
    pn += __shfl_xor(pn, 4);
    if ((tid & 7) == 0)
        atomicMax((int*)(knorm + h), __float_as_int(pn));

    const int vc = tid & 63;
    const int vr = (tid >> 6) * 8;      // k-range vr..vr+7 (same jt group)
    const float* vs = v + ((size_t)h * SEQ_LEN + s0 + vr) * HEAD_DIM + vc;
    bf16x4 vb0, vb1;
    #pragma unroll
    for (int j = 0; j < 4; ++j) {
        vb0[j] = (__bf16)vs[(size_t)j * HEAD_DIM];
        vb1[j] = (__bf16)vs[(size_t)(4 + j) * HEAD_DIM];
    }
    const int swzV = (vc & 7) << 4;
    *(bf16x4*)(vtimg + blk + ((vc * 64 + vpos(vr))     ^ swzV)) = vb0;
    *(bf16x4*)(vtimg + blk + ((vc * 64 + vpos(vr + 4)) ^ swzV)) = vb1;
}

// R17 structure (champion 42.6 us main) + R18 change: FIXED softmax bound.
// m_fixed = slope2*(kend-1-qpos) + scale2*||q||*max||k||*1.05 >= every score
// in this wave's KV range (ALiBi monotone in k + Cauchy-Schwarz), so
// p = exp2(s - m_fixed) <= 1 always: the per-iter max tree, 2 shfl_xor,
// defer branch, and alpha rescale are DELETED (the serial cross-lane chain
// between QK^T and PV). Far-k p underflow to 0 = true softmax behavior;
// the uniform shift cancels in acc/l. Merge math unchanged (m = m_fixed).
// LDS (65536 B): [0,32K) K [half][dbuf][2 sub][4096], [32K,64K) Vt same.
template <bool IMG>
__global__ __launch_bounds__(512, 2)
void attn_alibi_kernel(const float* __restrict__ q,
                       const float* __restrict__ k,
                       const float* __restrict__ v,
                       float* __restrict__ out,
                       const char* __restrict__ kimg,
                       const char* __restrict__ vtimg,
                       const float* __restrict__ knorm) {
    const int tid  = threadIdx.x;
    const int wave = tid >> 6;
    const int lane = tid & 63;
    const int col  = lane & 15;
    const int g    = lane >> 4;
    const int half = wave >> 2;
    const int w4   = wave & 3;

    const int h      = blockIdx.y;
    const int qbase  = blockIdx.x * 64 + w4 * 16;
    const int kstart = half * (NT * KVBLK);

    const float* qh = q + (size_t)h * SEQ_LEN * HEAD_DIM;
    const float* kh = k + (size_t)h * SEQ_LEN * HEAD_DIM;
    const float* vh = v + (size_t)h * SEQ_LEN * HEAD_DIM;

    __shared__ alignas(16) char smem[65536];
    char* kbase  = smem + half * 16384;
    char* vtbase = smem + 32768 + half * 16384;

    const float LOG2E  = 1.4426950408889634f;
    const float scale2 = 0.125f * LOG2E;
    const float slope  = exp2f(-0.5f * (float)(h + 1));
    const float slope2 = slope * LOG2E;

    // ---- Q B-fragments + ||q||^2: lane holds Q[qbase+col][c*32 + g*8 + b] ----
    bf16x8 qf[2];
    float qn2 = 0.0f;
    {
        const float* qr = qh + (size_t)(qbase + col) * HEAD_DIM + g * 8;
        #pragma unroll
        for (int c = 0; c < 2; ++c)
            #pragma unroll
            for (int b = 0; b < 8; ++b) {
                float x = qr[c * 32 + b];
                qn2 += x * x;
                qf[c][b] = (__bf16)x;
            }
    }
    qn2 += __shfl_xor(qn2, 16);
    qn2 += __shfl_xor(qn2, 32);

    // ---- fixed softmax bound for this wave's KV range ----
    float knmax;
    if constexpr (IMG) knmax = sqrtf(knorm[h]);
    else               knmax = 16.0f;   // conservative static bound
    const int   kend = kstart + NT * KVBLK;
    const float m = slope2 * (float)(kend - 1 - (qbase + col))
                  + scale2 * sqrtf(qn2) * knmax * 1.05f;

    // ALiBi minus bound: cbm[i][r] = slope2*(i*16+g*4+r - qpos) - m
    float cbm[4][4];
    #pragma unroll
    for (int i = 0; i < 4; ++i)
        #pragma unroll
        for (int r = 0; r < 4; ++r)
            cbm[i][r] = slope2 * (float)(i * 16 + g * 4 + r - (qbase + col)) - m;

    float l = 0.0f;               // per-lane partial (reduced after loop)
    f32x4 acc[4];
    #pragma unroll
    for (int dt = 0; dt < 4; ++dt) acc[dt] = (f32x4)0.0f;

    // ---- staging setup (256 threads per half) ----
    const int hid  = tid & 255;
    const int krow = hid >> 3;
    const int kcol = (hid & 7) * 8;
    const int vc   = hid & 63;
    const int vr   = (hid >> 6) * 8;

    const char* kis = nullptr; const char* vis = nullptr;
    const float* ksrc = nullptr; const float* vsrc = nullptr;
    char* kdst = nullptr; char* vtdst0 = nullptr; char* vtdst1 = nullptr;
    if constexpr (IMG) {
        const size_t base = ((size_t)h * NTILE_TOT + half * (NTILE_TOT / 2)) * 4096
                          + hid * 16;
        kis = kimg + base;  vis = vtimg + base;   // per-lane sources
#if HAVE_GLL
        kdst   = kbase + w4 * 1024;     // wave-uniform; HW adds lane*16
        vtdst0 = vtbase + w4 * 1024;
#else
        kdst   = kbase + hid * 16;
        vtdst0 = vtbase + hid * 16;
#endif
    } else {
        ksrc  = kh + (size_t)(kstart + krow) * HEAD_DIM + kcol;
        kdst  = kbase + krow * 128 + ((kcol * 2) ^ ((krow & 7) << 4));
        vsrc  = vh + (size_t)(kstart + vr) * HEAD_DIM + vc;
        const int swzV = (vc & 7) << 4;
        vtdst0 = vtbase + ((vc * 64 + vpos(vr))     ^ swzV);
        vtdst1 = vtbase + ((vc * 64 + vpos(vr + 4)) ^ swzV);
    }

    f32x4 kreg[2], vreg[2];          // non-GLL IMG: raw 16B chunks
    f32x4 kr[2][2];                  // direct path
    float vv[2][8];

    // ---- prologue: stage iteration 0 into buf 0 ----
    if constexpr (IMG) {
#if HAVE_GLL
        #pragma unroll
        for (int sb = 0; sb < 2; ++sb) {
            GLL16(kis + sb * 4096, kdst   + sb * 4096);
            GLL16(vis + sb * 4096, vtdst0 + sb * 4096);
        }
#else
        #pragma unroll
        for (int sb = 0; sb < 2; ++sb) {
            kreg[sb] = *(const f32x4*)(kis + sb * 4096);
            vreg[sb] = *(const f32x4*)(vis + sb * 4096);
            *(f32x4*)(kdst   + sb * 4096) = kreg[sb];
            *(f32x4*)(vtdst0 + sb * 4096) = vreg[sb];
        }
#endif
    } else {
        #pragma unroll
        for (int sb = 0; sb < 2; ++sb) {
            const float* ks = ksrc + (size_t)(sb * 32) * HEAD_DIM;
            const float* vs = vsrc + (size_t)(sb * 32) * HEAD_DIM;
            kr[sb][0] = *(const f32x4*)(ks);
            kr[sb][1] = *(const f32x4*)(ks + 4);
            #pragma unroll
            for (int j = 0; j < 8; ++j) vv[sb][j] = vs[(size_t)j * HEAD_DIM];
            bf16x8 kb16;
            bf16x4 vb0, vb1;
            #pragma unroll
            for (int b = 0; b < 4; ++b) {
                kb16[b] = (__bf16)kr[sb][0][b]; kb16[4 + b] = (__bf16)kr[sb][1][b];
                vb0[b] = (__bf16)vv[sb][b];     vb1[b] = (__bf16)vv[sb][4 + b];
            }
            *(bf16x8*)(kdst   + sb * 4096) = kb16;
            *(bf16x4*)(vtdst0 + sb * 4096) = vb0;
            *(bf16x4*)(vtdst1 + sb * 4096) = vb1;
        }
    }
    __syncthreads();

    for (int t = 0; t < NT; ++t) {
        const int kb  = kstart + t * KVBLK;
        const int buf = t & 1;
        const char* kbuf  = kbase + buf * 8192;
        const char* vtbuf = vtbase + buf * 8192;

        // ---- issue next-iteration DMA staging at loop top ----
#if HAVE_GLL
        if (IMG && t + 1 < NT) {
            const int nb = (t + 1) & 1;
            #pragma unroll
            for (int sb = 0; sb < 2; ++sb) {
                GLL16(kis + (size_t)((t + 1) * 2 + sb) * 4096,
                      kdst + nb * 8192 + sb * 4096);
                GLL16(vis + (size_t)((t + 1) * 2 + sb) * 4096,
                      vtdst0 + nb * 8192 + sb * 4096);
            }
        }
#endif

        // ---- S^T = K Q^T over 64 k-rows (2 sub-blocks x 2 jt) ----
        f32x4 sacc[4];
        #pragma unroll
        for (int i = 0; i < 4; ++i) sacc[i] = (f32x4)0.0f;
        __builtin_amdgcn_s_setprio(1);
        #pragma unroll
        for (int sb = 0; sb < 2; ++sb) {
            #pragma unroll
            for (int jt = 0; jt < 2; ++jt) {
                const int row = jt * 16 + col;
                const int i   = sb * 2 + jt;
                #pragma unroll
                for (int c = 0; c < 2; ++c) {
                    bf16x8 kf = *(const bf16x8*)(kbuf + sb * 4096 + row * 128
                                                 + ((c * 64 + g * 16) ^ ((row & 7) << 4)));
                    sacc[i] = __builtin_amdgcn_mfma_f32_16x16x32_bf16(kf, qf[c], sacc[i], 0, 0, 0);
                }
            }
        }
        __builtin_amdgcn_s_setprio(0);

        // ---- non-DMA paths: issue next-iteration staging loads ----
        if (t + 1 < NT) {
            if constexpr (IMG) {
#if !HAVE_GLL
                #pragma unroll
                for (int sb = 0; sb < 2; ++sb) {
                    kreg[sb] = *(const f32x4*)(kis + (size_t)((t + 1) * 2 + sb) * 4096);
                    vreg[sb] = *(const f32x4*)(vis + (size_t)((t + 1) * 2 + sb) * 4096);
                }
#endif
            } else {
                #pragma unroll
                for (int sb = 0; sb < 2; ++sb) {
                    const float* ks = ksrc + (size_t)((t + 1) * 64 + sb * 32) * HEAD_DIM;
                    const float* vs = vsrc + (size_t)((t + 1) * 64 + sb * 32) * HEAD_DIM;
                    kr[sb][0] = *(const f32x4*)(ks);
                    kr[sb][1] = *(const f32x4*)(ks + 4);
                    #pragma unroll
                    for (int j = 0; j < 8; ++j) vv[sb][j] = vs[(size_t)j * HEAD_DIM];
                }
            }
        }

        // ---- p = exp2(s - m_fixed); no max tree, no shfl, no rescale ----
        const float skb = slope2 * (float)kb;
        float p[4][4], y = 0.0f;
        #pragma unroll
        for (int i = 0; i < 4; ++i)
            #pragma unroll
            for (int r = 0; r < 4; ++r) {
                float sv = sacc[i][r] * scale2 + (cbm[i][r] + skb);
                p[i][r] = __builtin_amdgcn_exp2f(sv);
                y += p[i][r];
            }
        l += y;

#if HAVE_MFMA16
        // ---- ZERO-SHUFFLE PV: 8x b128, each feeding two K=16 MFMAs ----
        s16x4 pb[4];
        #pragma unroll
        for (int i = 0; i < 4; ++i) {
            bf16x4 pf;
            #pragma unroll
            for (int b = 0; b < 4; ++b) pf[b] = (__bf16)p[i][b];
            pb[i] = __builtin_bit_cast(s16x4, pf);
        }
        __builtin_amdgcn_s_setprio(1);
        #pragma unroll
        for (int dt = 0; dt < 4; ++dt) {
            const int vrow = dt * 16 + col;
            const int off  = (vrow * 64 + g * 16) ^ ((vrow & 7) << 4);
            #pragma unroll
            for (int sb = 0; sb < 2; ++sb) {
                bf16x8 vf = *(const bf16x8*)(vtbuf + sb * 4096 + off);
                bf16x4 vlo = __builtin_shufflevector(vf, vf, 0, 1, 2, 3);
                bf16x4 vhi = __builtin_shufflevector(vf, vf, 4, 5, 6, 7);
                acc[dt] = __builtin_amdgcn_mfma_f32_16x16x16bf16_1k(
                    __builtin_bit_cast(s16x4, vlo), pb[sb * 2 + 0], acc[dt], 0, 0, 0);
                acc[dt] = __builtin_amdgcn_mfma_f32_16x16x16bf16_1k(
                    __builtin_bit_cast(s16x4, vhi), pb[sb * 2 + 1], acc[dt], 0, 0, 0);
            }
        }
        __builtin_amdgcn_s_setprio(0);
#else
        // ---- fallback: per sub-block pack + 8-shfl permute + K=32 PV ----
        #pragma unroll
        for (int sb = 0; sb < 2; ++sb) {
            unsigned pk00 = pkbf(p[sb * 2][0],     p[sb * 2][1]);
            unsigned pk01 = pkbf(p[sb * 2][2],     p[sb * 2][3]);
            unsigned pk10 = pkbf(p[sb * 2 + 1][0], p[sb * 2 + 1][1]);
            unsigned pk11 = pkbf(p[sb * 2 + 1][2], p[sb * 2 + 1][3]);
            const int srcA = col + ((g & 1) << 5);
            const int srcB = srcA + 16;
            unsigned a00 = __shfl(pk00, srcA), a01 = __shfl(pk01, srcA);
            unsigned a10 = __shfl(pk10, srcA), a11 = __shfl(pk11, srcA);
            unsigned b00 = __shfl(pk00, srcB), b01 = __shfl(pk01, srcB);
            unsigned b10 = __shfl(pk10, srcB), b11 = __shfl(pk11, srcB);
            const bool hi = g >= 2;
            u32x4 pu;
            pu[0] = hi ? a10 : a00;
            pu[1] = hi ? a11 : a01;
            pu[2] = hi ? b10 : b00;
            pu[3] = hi ? b11 : b01;
            bf16x8 pf = __builtin_bit_cast(bf16x8, pu);
            #pragma unroll
            for (int dt = 0; dt < 4; ++dt) {
                const int vrow = dt * 16 + col;
                bf16x8 vf = *(const bf16x8*)(vtbuf + sb * 4096
                                + ((vrow * 64 + g * 16) ^ ((vrow & 7) << 4)));
                acc[dt] = __builtin_amdgcn_mfma_f32_16x16x32_bf16(vf, pf, acc[dt], 0, 0, 0);
            }
        }
#endif

        // ---- non-DMA paths: write next iteration into the other buffer ----
        if (t + 1 < NT) {
            const int nb = (t + 1) & 1;
            if constexpr (IMG) {
#if !HAVE_GLL
                #pragma unroll
                for (int sb = 0; sb < 2; ++sb) {
                    *(f32x4*)(kdst   + nb * 8192 + sb * 4096) = kreg[sb];
                    *(f32x4*)(vtdst0 + nb * 8192 + sb * 4096) = vreg[sb];
                }
#endif
            } else {
                #pragma unroll
                for (int sb = 0; sb < 2; ++sb) {
                    bf16x8 kb16;
                    bf16x4 vb0, vb1;
                    #pragma unroll
                    for (int b = 0; b < 4; ++b) {
                        kb16[b] = (__bf16)kr[sb][0][b]; kb16[4 + b] = (__bf16)kr[sb][1][b];
                        vb0[b] = (__bf16)vv[sb][b];     vb1[b] = (__bf16)vv[sb][4 + b];
                    }
                    *(bf16x8*)(kdst   + nb * 8192 + sb * 4096) = kb16;
                    *(bf16x4*)(vtdst0 + nb * 8192 + sb * 4096) = vb0;
                    *(bf16x4*)(vtdst1 + nb * 8192 + sb * 4096) = vb1;
                }
            }
        }
        __syncthreads();
    }

    // ---- deferred l reduction across g-groups ----
    l += __shfl_xor(l, 16);
    l += __shfl_xor(l, 32);

    // ---- merge halves (flash combine in O^T layout, base-2 domain) ----
    float* eacc = (float*)smem;            // [w4][q=col 16][d 64]
    float* eml  = (float*)(smem + 16384);  // [w4*16+col]*2

    if (half == 1) {
        #pragma unroll
        for (int dt = 0; dt < 4; ++dt)
            *(f32x4*)(eacc + w4 * 1024 + col * 64 + dt * 16 + g * 4) = acc[dt];
        if (g == 0) {
            eml[(w4 * 16 + col) * 2 + 0] = m;
            eml[(w4 * 16 + col) * 2 + 1] = l;
        }
    }
    __syncthreads();
    if (half == 0) {
        float m2 = eml[(w4 * 16 + col) * 2 + 0];
        float l2 = eml[(w4 * 16 + col) * 2 + 1];
        float mm = fmaxf(m, m2);
        float a1 = __builtin_amdgcn_exp2f(m - mm);
        float a2 = __builtin_amdgcn_exp2f(m2 - mm);
        float inv = 1.0f / (l * a1 + l2 * a2);
        float* orow = out + ((size_t)h * SEQ_LEN + qbase + col) * HEAD_DIM;
        #pragma unroll
        for (int dt = 0; dt < 4; ++dt) {
            f32x4 o2 = *(const f32x4*)(eacc + w4 * 1024 + col * 64 + dt * 16 + g * 4);
            *(f32x4*)(orow + dt * 16 + g * 4) = (acc[dt] * a1 + o2 * a2) * inv;
        }
    }
}

extern "C" void kernel_launch(void* const* d_in, const int* in_sizes, int n_in,
                              void* d_out, int out_size, void* d_ws, size_t ws_size,
                              hipStream_t stream) {
    const float* q = (const float*)d_in[0];
    const float* k = (const float*)d_in[1];
    const float* v = (const float*)d_in[2];
    float* out = (float*)d_out;

    const size_t imgBytes = (size_t)N_HEADS * NTILE_TOT * 4096;   // 4 MiB each
    const size_t need = 2 * imgBytes + N_HEADS * sizeof(float);

    dim3 grid(SEQ_LEN / 64, N_HEADS, 1);
    if (ws_size >= need) {
        char* kimg   = (char*)d_ws;
        char* vtimg  = kimg + imgBytes;
        float* knorm = (float*)(vtimg + imgBytes);
        hipMemsetAsync(knorm, 0, N_HEADS * sizeof(float), stream);
        prep_kernel<<<dim3(NTILE_TOT, N_HEADS, 1), dim3(256, 1, 1), 0, stream>>>(
            k, v, kimg, vtimg, knorm);
        attn_alibi_kernel<true><<<grid, dim3(512, 1, 1), 0, stream>>>(
            q, k, v, out, kimg, vtimg, knorm);
    } else {
        attn_alibi_kernel<false><<<grid, dim3(512, 1, 1), 0, stream>>>(
            q, k, v, out, nullptr, nullptr, nullptr);
    }
}

// Round 19
// 55.904 us; speedup vs baseline: 1.6246x; 1.6246x over previous
//
#include <hip/hip_runtime.h>
#include <hip/hip_bf16.h>
#include <stdint.h>
#include <math.h>

#define N_HEADS 16
#define HEAD_DIM 64
#define SEQ_LEN 2048
#define KVBLK 64                    // two verified 32-row sub-blocks per iter
#define NT 16                       // iterations per half-stream
#define NTILE_TOT (SEQ_LEN / 32)    // 32-row image tiles

typedef __bf16 bf16x8 __attribute__((ext_vector_type(8)));
typedef __bf16 bf16x4 __attribute__((ext_vector_type(4)));
typedef short  s16x4  __attribute__((ext_vector_type(4)));
typedef float  f32x4  __attribute__((ext_vector_type(4)));
typedef unsigned int u32x4 __attribute__((ext_vector_type(4)));

#if __has_builtin(__builtin_amdgcn_mfma_f32_16x16x16bf16_1k)
#define HAVE_MFMA16 1
#else
#define HAVE_MFMA16 0
#endif

#if __has_builtin(__builtin_amdgcn_global_load_lds)
#define HAVE_GLL 1
// DMA 16B/lane: LDS dest = wave-uniform base + lane*16 (HW adds lane offset);
// global source is per-lane (m97/m104/m173).
#define GLL16(gsrc, ldst)                                                     \
    __builtin_amdgcn_global_load_lds(                                         \
        (const __attribute__((address_space(1))) void*)(gsrc),                \
        (__attribute__((address_space(3))) void*)(ldst), 16, 0, 0)
#else
#define HAVE_GLL 0
#endif

static __device__ __forceinline__ unsigned pkbf(float a, float b) {
    union { __bf16 h[2]; unsigned u; } t;
    t.h[0] = (__bf16)a; t.h[1] = (__bf16)b;
    return t.u;
}

// Byte position of k (0..31) within a 64B Vt row.
// MFMA16: k-interleaved so chunk at g*16 = [jt=0,g,b0..3][jt=1,g,b0..3]
//         -> ONE ds_read_b128 feeds BOTH K=16 MFMAs of a sub-block (R16).
static __device__ __forceinline__ int vpos(int k) {
#if HAVE_MFMA16
    return ((k & 12) << 2) + ((k & 16) >> 1) + ((k & 3) << 1);
#else
    return k * 2;
#endif
}

// Prep: swizzled bf16 images of K (row-major) and Vt (transposed, k-interleaved
// rows), one 4 KB block per (head, 32-row tile) — byte-exact replicas of the
// LDS tiles. Also max ||K row||^2 per head for the fixed softmax bound.
// R19 fix: hierarchical reduce (shfl -> LDS -> thread0) so each WG issues ONE
// atomicMax, not 32 — R18's 32K contended atomics on 16 addresses serialized
// prep to 52 us (Guideline 12).
//   K : row-major bf16 [32][64], addr = row*128 + (off ^ ((row&7)<<4))
//   Vt: bf16 [64 d-rows][32 k], byte = (vc*64 + vpos(k)) ^ ((vc&7)<<4)
__global__ __launch_bounds__(256)
void prep_kernel(const float* __restrict__ k,
                 const float* __restrict__ v,
                 char* __restrict__ kimg,
                 char* __restrict__ vtimg,
                 float* __restrict__ knorm) {
    const int ts  = blockIdx.x;         // 32-row tile 0..63
    const int h   = blockIdx.y;
    const int tid = threadIdx.x;
    const int s0  = ts * 32;
    const size_t blk = ((size_t)h * NTILE_TOT + ts) * 4096;

    __shared__ float redmax[4];

    const int krow = tid >> 3;
    const int kcol = (tid & 7) * 8;
    const float* ks = k + ((size_t)h * SEQ_LEN + s0 + krow) * HEAD_DIM + kcol;
    f32x4 a = *(const f32x4*)ks;
    f32x4 b = *(const f32x4*)(ks + 4);
    bf16x8 kb;
    float pn = 0.0f;
    #pragma unroll
    for (int i = 0; i < 4; ++i) {
        kb[i] = (__bf16)a[i]; kb[4 + i] = (__bf16)b[i];
        pn += a[i] * a[i] + b[i] * b[i];
    }
    *(bf16x8*)(kimg + blk + krow * 128 + ((kcol * 2) ^ ((krow & 7) << 4))) = kb;

    // row ||K||^2 (8-lane groups) -> wave max -> block max -> 1 atomic/WG
    pn += __shfl_xor(pn, 1);
    pn += __shfl_xor(pn, 2);
    pn += __shfl_xor(pn, 4);
    float wmax = pn;
    wmax = fmaxf(wmax, __shfl_xor(wmax, 8));
    wmax = fmaxf(wmax, __shfl_xor(wmax, 16));
    wmax = fmaxf(wmax, __shfl_xor(wmax, 32));
    if ((tid & 63) == 0) redmax[tid >> 6] = wmax;

    const int vc = tid & 63;
    const int vr = (tid >> 6) * 8;      // k-range vr..vr+7 (same jt group)
    const float* vs = v + ((size_t)h * SEQ_LEN + s0 + vr) * HEAD_DIM + vc;
    bf16x4 vb0, vb1;
    #pragma unroll
    for (int j = 0; j < 4; ++j) {
        vb0[j] = (__bf16)vs[(size_t)j * HEAD_DIM];
        vb1[j] = (__bf16)vs[(size_t)(4 + j) * HEAD_DIM];
    }
    const int swzV = (vc & 7) << 4;
    *(bf16x4*)(vtimg + blk + ((vc * 64 + vpos(vr))     ^ swzV)) = vb0;
    *(bf16x4*)(vtimg + blk + ((vc * 64 + vpos(vr + 4)) ^ swzV)) = vb1;

    __syncthreads();
    if (tid == 0) {
        float bmax = fmaxf(fmaxf(redmax[0], redmax[1]),
                           fmaxf(redmax[2], redmax[3]));
        atomicMax((int*)(knorm + h), __float_as_int(bmax));
    }
}

// R18 main kernel (verified, ~37-38 us): FIXED softmax bound
// m_fixed = slope2*(kend-1-qpos) + scale2*||q||*max||k||*1.05 >= every score
// in this wave's KV range (ALiBi monotone in k + Cauchy-Schwarz), so
// p = exp2(s - m_fixed) <= 1 always: no per-iter max tree, no shfl, no
// rescale. Far-k p underflow to 0 = true softmax behavior; uniform shift
// cancels in acc/l. Merge math unchanged (m = m_fixed per half).
// LDS (65536 B): [0,32K) K [half][dbuf][2 sub][4096], [32K,64K) Vt same.
template <bool IMG>
__global__ __launch_bounds__(512, 2)
void attn_alibi_kernel(const float* __restrict__ q,
                       const float* __restrict__ k,
                       const float* __restrict__ v,
                       float* __restrict__ out,
                       const char* __restrict__ kimg,
                       const char* __restrict__ vtimg,
                       const float* __restrict__ knorm) {
    const int tid  = threadIdx.x;
    const int wave = tid >> 6;
    const int lane = tid & 63;
    const int col  = lane & 15;
    const int g    = lane >> 4;
    const int half = wave >> 2;
    const int w4   = wave & 3;

    const int h      = blockIdx.y;
    const int qbase  = blockIdx.x * 64 + w4 * 16;
    const int kstart = half * (NT * KVBLK);

    const float* qh = q + (size_t)h * SEQ_LEN * HEAD_DIM;
    const float* kh = k + (size_t)h * SEQ_LEN * HEAD_DIM;
    const float* vh = v + (size_t)h * SEQ_LEN * HEAD_DIM;

    __shared__ alignas(16) char smem[65536];
    char* kbase  = smem + half * 16384;
    char* vtbase = smem + 32768 + half * 16384;

    const float LOG2E  = 1.4426950408889634f;
    const float scale2 = 0.125f * LOG2E;
    const float slope  = exp2f(-0.5f * (float)(h + 1));
    const float slope2 = slope * LOG2E;

    // ---- Q B-fragments + ||q||^2 ----
    bf16x8 qf[2];
    float qn2 = 0.0f;
    {
        const float* qr = qh + (size_t)(qbase + col) * HEAD_DIM + g * 8;
        #pragma unroll
        for (int c = 0; c < 2; ++c)
            #pragma unroll
            for (int b = 0; b < 8; ++b) {
                float x = qr[c * 32 + b];
                qn2 += x * x;
                qf[c][b] = (__bf16)x;
            }
    }
    qn2 += __shfl_xor(qn2, 16);
    qn2 += __shfl_xor(qn2, 32);

    // ---- fixed softmax bound for this wave's KV range ----
    float knmax;
    if constexpr (IMG) knmax = sqrtf(knorm[h]);
    else               knmax = 16.0f;   // conservative static bound
    const int   kend = kstart + NT * KVBLK;
    const float m = slope2 * (float)(kend - 1 - (qbase + col))
                  + scale2 * sqrtf(qn2) * knmax * 1.05f;

    // ALiBi minus bound: cbm[i][r] = slope2*(i*16+g*4+r - qpos) - m
    float cbm[4][4];
    #pragma unroll
    for (int i = 0; i < 4; ++i)
        #pragma unroll
        for (int r = 0; r < 4; ++r)
            cbm[i][r] = slope2 * (float)(i * 16 + g * 4 + r - (qbase + col)) - m;

    float l = 0.0f;               // per-lane partial (reduced after loop)
    f32x4 acc[4];
    #pragma unroll
    for (int dt = 0; dt < 4; ++dt) acc[dt] = (f32x4)0.0f;

    // ---- staging setup (256 threads per half) ----
    const int hid  = tid & 255;
    const int krow = hid >> 3;
    const int kcol = (hid & 7) * 8;
    const int vc   = hid & 63;
    const int vr   = (hid >> 6) * 8;

    const char* kis = nullptr; const char* vis = nullptr;
    const float* ksrc = nullptr; const float* vsrc = nullptr;
    char* kdst = nullptr; char* vtdst0 = nullptr; char* vtdst1 = nullptr;
    if constexpr (IMG) {
        const size_t base = ((size_t)h * NTILE_TOT + half * (NTILE_TOT / 2)) * 4096
                          + hid * 16;
        kis = kimg + base;  vis = vtimg + base;   // per-lane sources
#if HAVE_GLL
        kdst   = kbase + w4 * 1024;     // wave-uniform; HW adds lane*16
        vtdst0 = vtbase + w4 * 1024;
#else
        kdst   = kbase + hid * 16;
        vtdst0 = vtbase + hid * 16;
#endif
    } else {
        ksrc  = kh + (size_t)(kstart + krow) * HEAD_DIM + kcol;
        kdst  = kbase + krow * 128 + ((kcol * 2) ^ ((krow & 7) << 4));
        vsrc  = vh + (size_t)(kstart + vr) * HEAD_DIM + vc;
        const int swzV = (vc & 7) << 4;
        vtdst0 = vtbase + ((vc * 64 + vpos(vr))     ^ swzV);
        vtdst1 = vtbase + ((vc * 64 + vpos(vr + 4)) ^ swzV);
    }

    f32x4 kreg[2], vreg[2];          // non-GLL IMG: raw 16B chunks
    f32x4 kr[2][2];                  // direct path
    float vv[2][8];

    // ---- prologue: stage iteration 0 into buf 0 ----
    if constexpr (IMG) {
#if HAVE_GLL
        #pragma unroll
        for (int sb = 0; sb < 2; ++sb) {
            GLL16(kis + sb * 4096, kdst   + sb * 4096);
            GLL16(vis + sb * 4096, vtdst0 + sb * 4096);
        }
#else
        #pragma unroll
        for (int sb = 0; sb < 2; ++sb) {
            kreg[sb] = *(const f32x4*)(kis + sb * 4096);
            vreg[sb] = *(const f32x4*)(vis + sb * 4096);
            *(f32x4*)(kdst   + sb * 4096) = kreg[sb];
            *(f32x4*)(vtdst0 + sb * 4096) = vreg[sb];
        }
#endif
    } else {
        #pragma unroll
        for (int sb = 0; sb < 2; ++sb) {
            const float* ks = ksrc + (size_t)(sb * 32) * HEAD_DIM;
            const float* vs = vsrc + (size_t)(sb * 32) * HEAD_DIM;
            kr[sb][0] = *(const f32x4*)(ks);
            kr[sb][1] = *(const f32x4*)(ks + 4);
            #pragma unroll
            for (int j = 0; j < 8; ++j) vv[sb][j] = vs[(size_t)j * HEAD_DIM];
            bf16x8 kb16;
            bf16x4 vb0, vb1;
            #pragma unroll
            for (int b = 0; b < 4; ++b) {
                kb16[b] = (__bf16)kr[sb][0][b]; kb16[4 + b] = (__bf16)kr[sb][1][b];
                vb0[b] = (__bf16)vv[sb][b];     vb1[b] = (__bf16)vv[sb][4 + b];
            }
            *(bf16x8*)(kdst   + sb * 4096) = kb16;
            *(bf16x4*)(vtdst0 + sb * 4096) = vb0;
            *(bf16x4*)(vtdst1 + sb * 4096) = vb1;
        }
    }
    __syncthreads();

    for (int t = 0; t < NT; ++t) {
        const int kb  = kstart + t * KVBLK;
        const int buf = t & 1;
        const char* kbuf  = kbase + buf * 8192;
        const char* vtbuf = vtbase + buf * 8192;

        // ---- issue next-iteration DMA staging at loop top ----
#if HAVE_GLL
        if (IMG && t + 1 < NT) {
            const int nb = (t + 1) & 1;
            #pragma unroll
            for (int sb = 0; sb < 2; ++sb) {
                GLL16(kis + (size_t)((t + 1) * 2 + sb) * 4096,
                      kdst + nb * 8192 + sb * 4096);
                GLL16(vis + (size_t)((t + 1) * 2 + sb) * 4096,
                      vtdst0 + nb * 8192 + sb * 4096);
            }
        }
#endif

        // ---- S^T = K Q^T over 64 k-rows (2 sub-blocks x 2 jt) ----
        f32x4 sacc[4];
        #pragma unroll
        for (int i = 0; i < 4; ++i) sacc[i] = (f32x4)0.0f;
        __builtin_amdgcn_s_setprio(1);
        #pragma unroll
        for (int sb = 0; sb < 2; ++sb) {
            #pragma unroll
            for (int jt = 0; jt < 2; ++jt) {
                const int row = jt * 16 + col;
                const int i   = sb * 2 + jt;
                #pragma unroll
                for (int c = 0; c < 2; ++c) {
                    bf16x8 kf = *(const bf16x8*)(kbuf + sb * 4096 + row * 128
                                                 + ((c * 64 + g * 16) ^ ((row & 7) << 4)));
                    sacc[i] = __builtin_amdgcn_mfma_f32_16x16x32_bf16(kf, qf[c], sacc[i], 0, 0, 0);
                }
            }
        }
        __builtin_amdgcn_s_setprio(0);

        // ---- non-DMA paths: issue next-iteration staging loads ----
        if (t + 1 < NT) {
            if constexpr (IMG) {
#if !HAVE_GLL
                #pragma unroll
                for (int sb = 0; sb < 2; ++sb) {
                    kreg[sb] = *(const f32x4*)(kis + (size_t)((t + 1) * 2 + sb) * 4096);
                    vreg[sb] = *(const f32x4*)(vis + (size_t)((t + 1) * 2 + sb) * 4096);
                }
#endif
            } else {
                #pragma unroll
                for (int sb = 0; sb < 2; ++sb) {
                    const float* ks = ksrc + (size_t)((t + 1) * 64 + sb * 32) * HEAD_DIM;
                    const float* vs = vsrc + (size_t)((t + 1) * 64 + sb * 32) * HEAD_DIM;
                    kr[sb][0] = *(const f32x4*)(ks);
                    kr[sb][1] = *(const f32x4*)(ks + 4);
                    #pragma unroll
                    for (int j = 0; j < 8; ++j) vv[sb][j] = vs[(size_t)j * HEAD_DIM];
                }
            }
        }

        // ---- p = exp2(s - m_fixed); no max tree, no shfl, no rescale ----
        const float skb = slope2 * (float)kb;
        float p[4][4], y = 0.0f;
        #pragma unroll
        for (int i = 0; i < 4; ++i)
            #pragma unroll
            for (int r = 0; r < 4; ++r) {
                float sv = sacc[i][r] * scale2 + (cbm[i][r] + skb);
                p[i][r] = __builtin_amdgcn_exp2f(sv);
                y += p[i][r];
            }
        l += y;

#if HAVE_MFMA16
        // ---- ZERO-SHUFFLE PV: 8x b128, each feeding two K=16 MFMAs ----
        s16x4 pb[4];
        #pragma unroll
        for (int i = 0; i < 4; ++i) {
            bf16x4 pf;
            #pragma unroll
            for (int b = 0; b < 4; ++b) pf[b] = (__bf16)p[i][b];
            pb[i] = __builtin_bit_cast(s16x4, pf);
        }
        __builtin_amdgcn_s_setprio(1);
        #pragma unroll
        for (int dt = 0; dt < 4; ++dt) {
            const int vrow = dt * 16 + col;
            const int off  = (vrow * 64 + g * 16) ^ ((vrow & 7) << 4);
            #pragma unroll
            for (int sb = 0; sb < 2; ++sb) {
                bf16x8 vf = *(const bf16x8*)(vtbuf + sb * 4096 + off);
                bf16x4 vlo = __builtin_shufflevector(vf, vf, 0, 1, 2, 3);
                bf16x4 vhi = __builtin_shufflevector(vf, vf, 4, 5, 6, 7);
                acc[dt] = __builtin_amdgcn_mfma_f32_16x16x16bf16_1k(
                    __builtin_bit_cast(s16x4, vlo), pb[sb * 2 + 0], acc[dt], 0, 0, 0);
                acc[dt] = __builtin_amdgcn_mfma_f32_16x16x16bf16_1k(
                    __builtin_bit_cast(s16x4, vhi), pb[sb * 2 + 1], acc[dt], 0, 0, 0);
            }
        }
        __builtin_amdgcn_s_setprio(0);
#else
        // ---- fallback: per sub-block pack + 8-shfl permute + K=32 PV ----
        #pragma unroll
        for (int sb = 0; sb < 2; ++sb) {
            unsigned pk00 = pkbf(p[sb * 2][0],     p[sb * 2][1]);
            unsigned pk01 = pkbf(p[sb * 2][2],     p[sb * 2][3]);
            unsigned pk10 = pkbf(p[sb * 2 + 1][0], p[sb * 2 + 1][1]);
            unsigned pk11 = pkbf(p[sb * 2 + 1][2], p[sb * 2 + 1][3]);
            const int srcA = col + ((g & 1) << 5);
            const int srcB = srcA + 16;
            unsigned a00 = __shfl(pk00, srcA), a01 = __shfl(pk01, srcA);
            unsigned a10 = __shfl(pk10, srcA), a11 = __shfl(pk11, srcA);
            unsigned b00 = __shfl(pk00, srcB), b01 = __shfl(pk01, srcB);
            unsigned b10 = __shfl(pk10, srcB), b11 = __shfl(pk11, srcB);
            const bool hi = g >= 2;
            u32x4 pu;
            pu[0] = hi ? a10 : a00;
            pu[1] = hi ? a11 : a01;
            pu[2] = hi ? b10 : b00;
            pu[3] = hi ? b11 : b01;
            bf16x8 pf = __builtin_bit_cast(bf16x8, pu);
            #pragma unroll
            for (int dt = 0; dt < 4; ++dt) {
                const int vrow = dt * 16 + col;
                bf16x8 vf = *(const bf16x8*)(vtbuf + sb * 4096
                                + ((vrow * 64 + g * 16) ^ ((vrow & 7) << 4)));
                acc[dt] = __builtin_amdgcn_mfma_f32_16x16x32_bf16(vf, pf, acc[dt], 0, 0, 0);
            }
        }
#endif

        // ---- non-DMA paths: write next iteration into the other buffer ----
        if (t + 1 < NT) {
            const int nb = (t + 1) & 1;
            if constexpr (IMG) {
#if !HAVE_GLL
                #pragma unroll
                for (int sb = 0; sb < 2; ++sb) {
                    *(f32x4*)(kdst   + nb * 8192 + sb * 4096) = kreg[sb];
                    *(f32x4*)(vtdst0 + nb * 8192 + sb * 4096) = vreg[sb];
                }
#endif
            } else {
                #pragma unroll
                for (int sb = 0; sb < 2; ++sb) {
                    bf16x8 kb16;
                    bf16x4 vb0, vb1;
                    #pragma unroll
                    for (int b = 0; b < 4; ++b) {
                        kb16[b] = (__bf16)kr[sb][0][b]; kb16[4 + b] = (__bf16)kr[sb][1][b];
                        vb0[b] = (__bf16)vv[sb][b];     vb1[b] = (__bf16)vv[sb][4 + b];
                    }
                    *(bf16x8*)(kdst   + nb * 8192 + sb * 4096) = kb16;
                    *(bf16x4*)(vtdst0 + nb * 8192 + sb * 4096) = vb0;
                    *(bf16x4*)(vtdst1 + nb * 8192 + sb * 4096) = vb1;
                }
            }
        }
        __syncthreads();
    }

    // ---- deferred l reduction across g-groups ----
    l += __shfl_xor(l, 16);
    l += __shfl_xor(l, 32);

    // ---- merge halves (flash combine in O^T layout, base-2 domain) ----
    float* eacc = (float*)smem;            // [w4][q=col 16][d 64]
    float* eml  = (float*)(smem + 16384);  // [w4*16+col]*2

    if (half == 1) {
        #pragma unroll
        for (int dt = 0; dt < 4; ++dt)
            *(f32x4*)(eacc + w4 * 1024 + col * 64 + dt * 16 + g * 4) = acc[dt];
        if (g == 0) {
            eml[(w4 * 16 + col) * 2 + 0] = m;
            eml[(w4 * 16 + col) * 2 + 1] = l;
        }
    }
    __syncthreads();
    if (half == 0) {
        float m2 = eml[(w4 * 16 + col) * 2 + 0];
        float l2 = eml[(w4 * 16 + col) * 2 + 1];
        float mm = fmaxf(m, m2);
        float a1 = __builtin_amdgcn_exp2f(m - mm);
        float a2 = __builtin_amdgcn_exp2f(m2 - mm);
        float inv = 1.0f / (l * a1 + l2 * a2);
        float* orow = out + ((size_t)h * SEQ_LEN + qbase + col) * HEAD_DIM;
        #pragma unroll
        for (int dt = 0; dt < 4; ++dt) {
            f32x4 o2 = *(const f32x4*)(eacc + w4 * 1024 + col * 64 + dt * 16 + g * 4);
            *(f32x4*)(orow + dt * 16 + g * 4) = (acc[dt] * a1 + o2 * a2) * inv;
        }
    }
}

extern "C" void kernel_launch(void* const* d_in, const int* in_sizes, int n_in,
                              void* d_out, int out_size, void* d_ws, size_t ws_size,
                              hipStream_t stream) {
    const float* q = (const float*)d_in[0];
    const float* k = (const float*)d_in[1];
    const float* v = (const float*)d_in[2];
    float* out = (float*)d_out;

    const size_t imgBytes = (size_t)N_HEADS * NTILE_TOT * 4096;   // 4 MiB each
    const size_t need = 2 * imgBytes + N_HEADS * sizeof(float);

    dim3 grid(SEQ_LEN / 64, N_HEADS, 1);
    if (ws_size >= need) {
        char* kimg   = (char*)d_ws;
        char* vtimg  = kimg + imgBytes;
        float* knorm = (float*)(vtimg + imgBytes);
        hipMemsetAsync(knorm, 0, N_HEADS * sizeof(float), stream);
        prep_kernel<<<dim3(NTILE_TOT, N_HEADS, 1), dim3(256, 1, 1), 0, stream>>>(
            k, v, kimg, vtimg, knorm);
        attn_alibi_kernel<true><<<grid, dim3(512, 1, 1), 0, stream>>>(
            q, k, v, out, kimg, vtimg, knorm);
    } else {
        attn_alibi_kernel<false><<<grid, dim3(512, 1, 1), 0, stream>>>(
            q, k, v, out, nullptr, nullptr, nullptr);
    }
}

// Round 20
// 43.390 us; speedup vs baseline: 2.0931x; 1.2884x over previous
//
#include <hip/hip_runtime.h>
#include <hip/hip_bf16.h>
#include <stdint.h>
#include <math.h>

#define N_HEADS 16
#define HEAD_DIM 64
#define SEQ_LEN 2048
#define KVBLK 64                    // two verified 32-row sub-blocks per iter
#define NT 16                       // iterations per half-stream
#define NTILE_TOT (SEQ_LEN / 32)    // 32-row image tiles

typedef __bf16 bf16x8 __attribute__((ext_vector_type(8)));
typedef __bf16 bf16x4 __attribute__((ext_vector_type(4)));
typedef short  s16x4  __attribute__((ext_vector_type(4)));
typedef float  f32x4  __attribute__((ext_vector_type(4)));
typedef unsigned int u32x4 __attribute__((ext_vector_type(4)));

#if __has_builtin(__builtin_amdgcn_mfma_f32_16x16x16bf16_1k)
#define HAVE_MFMA16 1
#else
#define HAVE_MFMA16 0
#endif

#if __has_builtin(__builtin_amdgcn_global_load_lds)
#define HAVE_GLL 1
// DMA 16B/lane: LDS dest = wave-uniform base + lane*16 (HW adds lane offset);
// global source is per-lane (m97/m104/m173).
#define GLL16(gsrc, ldst)                                                     \
    __builtin_amdgcn_global_load_lds(                                         \
        (const __attribute__((address_space(1))) void*)(gsrc),                \
        (__attribute__((address_space(3))) void*)(ldst), 16, 0, 0)
#else
#define HAVE_GLL 0
#endif

static __device__ __forceinline__ unsigned pkbf(float a, float b) {
    union { __bf16 h[2]; unsigned u; } t;
    t.h[0] = (__bf16)a; t.h[1] = (__bf16)b;
    return t.u;
}

// Byte position of k (0..31) within a 64B Vt row.
// MFMA16: k-interleaved so chunk at g*16 = [jt=0,g,b0..3][jt=1,g,b0..3]
//         -> ONE ds_read_b128 feeds BOTH K=16 MFMAs of a sub-block (R16).
static __device__ __forceinline__ int vpos(int k) {
#if HAVE_MFMA16
    return ((k & 12) << 2) + ((k & 16) >> 1) + ((k & 3) << 1);
#else
    return k * 2;
#endif
}

// Prep: swizzled bf16 images of K (row-major) and Vt (transposed, k-interleaved
// rows), one 4 KB block per (head, 32-row tile) — byte-exact replicas of the
// LDS tiles. Also per-TILE max ||K row||^2 via plain store into its own slot
// (tilemax[h*64+ts]) — R20 fix: no atomics, no zero-init, no per-launch memset
// (R19's 64B hipMemsetAsync replayed as a ~43us fillBuffer dispatch!).
//   K : row-major bf16 [32][64], addr = row*128 + (off ^ ((row&7)<<4))
//   Vt: bf16 [64 d-rows][32 k], byte = (vc*64 + vpos(k)) ^ ((vc&7)<<4)
__global__ __launch_bounds__(256)
void prep_kernel(const float* __restrict__ k,
                 const float* __restrict__ v,
                 char* __restrict__ kimg,
                 char* __restrict__ vtimg,
                 float* __restrict__ tilemax) {
    const int ts  = blockIdx.x;         // 32-row tile 0..63
    const int h   = blockIdx.y;
    const int tid = threadIdx.x;
    const int s0  = ts * 32;
    const size_t blk = ((size_t)h * NTILE_TOT + ts) * 4096;

    __shared__ float redmax[4];

    const int krow = tid >> 3;
    const int kcol = (tid & 7) * 8;
    const float* ks = k + ((size_t)h * SEQ_LEN + s0 + krow) * HEAD_DIM + kcol;
    f32x4 a = *(const f32x4*)ks;
    f32x4 b = *(const f32x4*)(ks + 4);
    bf16x8 kb;
    float pn = 0.0f;
    #pragma unroll
    for (int i = 0; i < 4; ++i) {
        kb[i] = (__bf16)a[i]; kb[4 + i] = (__bf16)b[i];
        pn += a[i] * a[i] + b[i] * b[i];
    }
    *(bf16x8*)(kimg + blk + krow * 128 + ((kcol * 2) ^ ((krow & 7) << 4))) = kb;

    // row ||K||^2 (8-lane groups) -> wave max -> block max -> 1 plain store
    pn += __shfl_xor(pn, 1);
    pn += __shfl_xor(pn, 2);
    pn += __shfl_xor(pn, 4);
    float wmax = pn;
    wmax = fmaxf(wmax, __shfl_xor(wmax, 8));
    wmax = fmaxf(wmax, __shfl_xor(wmax, 16));
    wmax = fmaxf(wmax, __shfl_xor(wmax, 32));
    if ((tid & 63) == 0) redmax[tid >> 6] = wmax;

    const int vc = tid & 63;
    const int vr = (tid >> 6) * 8;      // k-range vr..vr+7 (same jt group)
    const float* vs = v + ((size_t)h * SEQ_LEN + s0 + vr) * HEAD_DIM + vc;
    bf16x4 vb0, vb1;
    #pragma unroll
    for (int j = 0; j < 4; ++j) {
        vb0[j] = (__bf16)vs[(size_t)j * HEAD_DIM];
        vb1[j] = (__bf16)vs[(size_t)(4 + j) * HEAD_DIM];
    }
    const int swzV = (vc & 7) << 4;
    *(bf16x4*)(vtimg + blk + ((vc * 64 + vpos(vr))     ^ swzV)) = vb0;
    *(bf16x4*)(vtimg + blk + ((vc * 64 + vpos(vr + 4)) ^ swzV)) = vb1;

    __syncthreads();
    if (tid == 0) {
        tilemax[h * NTILE_TOT + ts] = fmaxf(fmaxf(redmax[0], redmax[1]),
                                            fmaxf(redmax[2], redmax[3]));
    }
}

// R18 main kernel (verified, ~37-38 us): FIXED softmax bound
// m_fixed = slope2*(kend-1-qpos) + scale2*||q||*max||k||*1.05 >= every score
// in this wave's KV range (ALiBi monotone in k + Cauchy-Schwarz), so
// p = exp2(s - m_fixed) <= 1 always: no per-iter max tree, no shfl, no
// rescale. Far-k p underflow to 0 = true softmax behavior; uniform shift
// cancels in acc/l. Merge math unchanged (m = m_fixed per half).
// knmax from the per-tile maxes: 1 load + 6 shfl fmax, init-only (R20).
// LDS (65536 B): [0,32K) K [half][dbuf][2 sub][4096], [32K,64K) Vt same.
template <bool IMG>
__global__ __launch_bounds__(512, 2)
void attn_alibi_kernel(const float* __restrict__ q,
                       const float* __restrict__ k,
                       const float* __restrict__ v,
                       float* __restrict__ out,
                       const char* __restrict__ kimg,
                       const char* __restrict__ vtimg,
                       const float* __restrict__ tilemax) {
    const int tid  = threadIdx.x;
    const int wave = tid >> 6;
    const int lane = tid & 63;
    const int col  = lane & 15;
    const int g    = lane >> 4;
    const int half = wave >> 2;
    const int w4   = wave & 3;

    const int h      = blockIdx.y;
    const int qbase  = blockIdx.x * 64 + w4 * 16;
    const int kstart = half * (NT * KVBLK);

    const float* qh = q + (size_t)h * SEQ_LEN * HEAD_DIM;
    const float* kh = k + (size_t)h * SEQ_LEN * HEAD_DIM;
    const float* vh = v + (size_t)h * SEQ_LEN * HEAD_DIM;

    __shared__ alignas(16) char smem[65536];
    char* kbase  = smem + half * 16384;
    char* vtbase = smem + 32768 + half * 16384;

    const float LOG2E  = 1.4426950408889634f;
    const float scale2 = 0.125f * LOG2E;
    const float slope  = exp2f(-0.5f * (float)(h + 1));
    const float slope2 = slope * LOG2E;

    // ---- Q B-fragments + ||q||^2 ----
    bf16x8 qf[2];
    float qn2 = 0.0f;
    {
        const float* qr = qh + (size_t)(qbase + col) * HEAD_DIM + g * 8;
        #pragma unroll
        for (int c = 0; c < 2; ++c)
            #pragma unroll
            for (int b = 0; b < 8; ++b) {
                float x = qr[c * 32 + b];
                qn2 += x * x;
                qf[c][b] = (__bf16)x;
            }
    }
    qn2 += __shfl_xor(qn2, 16);
    qn2 += __shfl_xor(qn2, 32);

    // ---- fixed softmax bound: knmax from per-tile maxes (init-only) ----
    float knmax;
    if constexpr (IMG) {
        float tm = tilemax[h * NTILE_TOT + lane];
        tm = fmaxf(tm, __shfl_xor(tm, 1));
        tm = fmaxf(tm, __shfl_xor(tm, 2));
        tm = fmaxf(tm, __shfl_xor(tm, 4));
        tm = fmaxf(tm, __shfl_xor(tm, 8));
        tm = fmaxf(tm, __shfl_xor(tm, 16));
        tm = fmaxf(tm, __shfl_xor(tm, 32));
        knmax = sqrtf(tm);
    } else {
        knmax = 16.0f;   // conservative static bound
    }
    const int   kend = kstart + NT * KVBLK;
    const float m = slope2 * (float)(kend - 1 - (qbase + col))
                  + scale2 * sqrtf(qn2) * knmax * 1.05f;

    // ALiBi minus bound: cbm[i][r] = slope2*(i*16+g*4+r - qpos) - m
    float cbm[4][4];
    #pragma unroll
    for (int i = 0; i < 4; ++i)
        #pragma unroll
        for (int r = 0; r < 4; ++r)
            cbm[i][r] = slope2 * (float)(i * 16 + g * 4 + r - (qbase + col)) - m;

    float l = 0.0f;               // per-lane partial (reduced after loop)
    f32x4 acc[4];
    #pragma unroll
    for (int dt = 0; dt < 4; ++dt) acc[dt] = (f32x4)0.0f;

    // ---- staging setup (256 threads per half) ----
    const int hid  = tid & 255;
    const int krow = hid >> 3;
    const int kcol = (hid & 7) * 8;
    const int vc   = hid & 63;
    const int vr   = (hid >> 6) * 8;

    const char* kis = nullptr; const char* vis = nullptr;
    const float* ksrc = nullptr; const float* vsrc = nullptr;
    char* kdst = nullptr; char* vtdst0 = nullptr; char* vtdst1 = nullptr;
    if constexpr (IMG) {
        const size_t base = ((size_t)h * NTILE_TOT + half * (NTILE_TOT / 2)) * 4096
                          + hid * 16;
        kis = kimg + base;  vis = vtimg + base;   // per-lane sources
#if HAVE_GLL
        kdst   = kbase + w4 * 1024;     // wave-uniform; HW adds lane*16
        vtdst0 = vtbase + w4 * 1024;
#else
        kdst   = kbase + hid * 16;
        vtdst0 = vtbase + hid * 16;
#endif
    } else {
        ksrc  = kh + (size_t)(kstart + krow) * HEAD_DIM + kcol;
        kdst  = kbase + krow * 128 + ((kcol * 2) ^ ((krow & 7) << 4));
        vsrc  = vh + (size_t)(kstart + vr) * HEAD_DIM + vc;
        const int swzV = (vc & 7) << 4;
        vtdst0 = vtbase + ((vc * 64 + vpos(vr))     ^ swzV);
        vtdst1 = vtbase + ((vc * 64 + vpos(vr + 4)) ^ swzV);
    }

    f32x4 kreg[2], vreg[2];          // non-GLL IMG: raw 16B chunks
    f32x4 kr[2][2];                  // direct path
    float vv[2][8];

    // ---- prologue: stage iteration 0 into buf 0 ----
    if constexpr (IMG) {
#if HAVE_GLL
        #pragma unroll
        for (int sb = 0; sb < 2; ++sb) {
            GLL16(kis + sb * 4096, kdst   + sb * 4096);
            GLL16(vis + sb * 4096, vtdst0 + sb * 4096);
        }
#else
        #pragma unroll
        for (int sb = 0; sb < 2; ++sb) {
            kreg[sb] = *(const f32x4*)(kis + sb * 4096);
            vreg[sb] = *(const f32x4*)(vis + sb * 4096);
            *(f32x4*)(kdst   + sb * 4096) = kreg[sb];
            *(f32x4*)(vtdst0 + sb * 4096) = vreg[sb];
        }
#endif
    } else {
        #pragma unroll
        for (int sb = 0; sb < 2; ++sb) {
            const float* ks = ksrc + (size_t)(sb * 32) * HEAD_DIM;
            const float* vs = vsrc + (size_t)(sb * 32) * HEAD_DIM;
            kr[sb][0] = *(const f32x4*)(ks);
            kr[sb][1] = *(const f32x4*)(ks + 4);
            #pragma unroll
            for (int j = 0; j < 8; ++j) vv[sb][j] = vs[(size_t)j * HEAD_DIM];
            bf16x8 kb16;
            bf16x4 vb0, vb1;
            #pragma unroll
            for (int b = 0; b < 4; ++b) {
                kb16[b] = (__bf16)kr[sb][0][b]; kb16[4 + b] = (__bf16)kr[sb][1][b];
                vb0[b] = (__bf16)vv[sb][b];     vb1[b] = (__bf16)vv[sb][4 + b];
            }
            *(bf16x8*)(kdst   + sb * 4096) = kb16;
            *(bf16x4*)(vtdst0 + sb * 4096) = vb0;
            *(bf16x4*)(vtdst1 + sb * 4096) = vb1;
        }
    }
    __syncthreads();

    for (int t = 0; t < NT; ++t) {
        const int kb  = kstart + t * KVBLK;
        const int buf = t & 1;
        const char* kbuf  = kbase + buf * 8192;
        const char* vtbuf = vtbase + buf * 8192;

        // ---- issue next-iteration DMA staging at loop top ----
#if HAVE_GLL
        if (IMG && t + 1 < NT) {
            const int nb = (t + 1) & 1;
            #pragma unroll
            for (int sb = 0; sb < 2; ++sb) {
                GLL16(kis + (size_t)((t + 1) * 2 + sb) * 4096,
                      kdst + nb * 8192 + sb * 4096);
                GLL16(vis + (size_t)((t + 1) * 2 + sb) * 4096,
                      vtdst0 + nb * 8192 + sb * 4096);
            }
        }
#endif

        // ---- S^T = K Q^T over 64 k-rows (2 sub-blocks x 2 jt) ----
        f32x4 sacc[4];
        #pragma unroll
        for (int i = 0; i < 4; ++i) sacc[i] = (f32x4)0.0f;
        __builtin_amdgcn_s_setprio(1);
        #pragma unroll
        for (int sb = 0; sb < 2; ++sb) {
            #pragma unroll
            for (int jt = 0; jt < 2; ++jt) {
                const int row = jt * 16 + col;
                const int i   = sb * 2 + jt;
                #pragma unroll
                for (int c = 0; c < 2; ++c) {
                    bf16x8 kf = *(const bf16x8*)(kbuf + sb * 4096 + row * 128
                                                 + ((c * 64 + g * 16) ^ ((row & 7) << 4)));
                    sacc[i] = __builtin_amdgcn_mfma_f32_16x16x32_bf16(kf, qf[c], sacc[i], 0, 0, 0);
                }
            }
        }
        __builtin_amdgcn_s_setprio(0);

        // ---- non-DMA paths: issue next-iteration staging loads ----
        if (t + 1 < NT) {
            if constexpr (IMG) {
#if !HAVE_GLL
                #pragma unroll
                for (int sb = 0; sb < 2; ++sb) {
                    kreg[sb] = *(const f32x4*)(kis + (size_t)((t + 1) * 2 + sb) * 4096);
                    vreg[sb] = *(const f32x4*)(vis + (size_t)((t + 1) * 2 + sb) * 4096);
                }
#endif
            } else {
                #pragma unroll
                for (int sb = 0; sb < 2; ++sb) {
                    const float* ks = ksrc + (size_t)((t + 1) * 64 + sb * 32) * HEAD_DIM;
                    const float* vs = vsrc + (size_t)((t + 1) * 64 + sb * 32) * HEAD_DIM;
                    kr[sb][0] = *(const f32x4*)(ks);
                    kr[sb][1] = *(const f32x4*)(ks + 4);
                    #pragma unroll
                    for (int j = 0; j < 8; ++j) vv[sb][j] = vs[(size_t)j * HEAD_DIM];
                }
            }
        }

        // ---- p = exp2(s - m_fixed); no max tree, no shfl, no rescale ----
        const float skb = slope2 * (float)kb;
        float p[4][4], y = 0.0f;
        #pragma unroll
        for (int i = 0; i < 4; ++i)
            #pragma unroll
            for (int r = 0; r < 4; ++r) {
                float sv = sacc[i][r] * scale2 + (cbm[i][r] + skb);
                p[i][r] = __builtin_amdgcn_exp2f(sv);
                y += p[i][r];
            }
        l += y;

#if HAVE_MFMA16
        // ---- ZERO-SHUFFLE PV: 8x b128, each feeding two K=16 MFMAs ----
        s16x4 pb[4];
        #pragma unroll
        for (int i = 0; i < 4; ++i) {
            bf16x4 pf;
            #pragma unroll
            for (int b = 0; b < 4; ++b) pf[b] = (__bf16)p[i][b];
            pb[i] = __builtin_bit_cast(s16x4, pf);
        }
        __builtin_amdgcn_s_setprio(1);
        #pragma unroll
        for (int dt = 0; dt < 4; ++dt) {
            const int vrow = dt * 16 + col;
            const int off  = (vrow * 64 + g * 16) ^ ((vrow & 7) << 4);
            #pragma unroll
            for (int sb = 0; sb < 2; ++sb) {
                bf16x8 vf = *(const bf16x8*)(vtbuf + sb * 4096 + off);
                bf16x4 vlo = __builtin_shufflevector(vf, vf, 0, 1, 2, 3);
                bf16x4 vhi = __builtin_shufflevector(vf, vf, 4, 5, 6, 7);
                acc[dt] = __builtin_amdgcn_mfma_f32_16x16x16bf16_1k(
                    __builtin_bit_cast(s16x4, vlo), pb[sb * 2 + 0], acc[dt], 0, 0, 0);
                acc[dt] = __builtin_amdgcn_mfma_f32_16x16x16bf16_1k(
                    __builtin_bit_cast(s16x4, vhi), pb[sb * 2 + 1], acc[dt], 0, 0, 0);
            }
        }
        __builtin_amdgcn_s_setprio(0);
#else
        // ---- fallback: per sub-block pack + 8-shfl permute + K=32 PV ----
        #pragma unroll
        for (int sb = 0; sb < 2; ++sb) {
            unsigned pk00 = pkbf(p[sb * 2][0],     p[sb * 2][1]);
            unsigned pk01 = pkbf(p[sb * 2][2],     p[sb * 2][3]);
            unsigned pk10 = pkbf(p[sb * 2 + 1][0], p[sb * 2 + 1][1]);
            unsigned pk11 = pkbf(p[sb * 2 + 1][2], p[sb * 2 + 1][3]);
            const int srcA = col + ((g & 1) << 5);
            const int srcB = srcA + 16;
            unsigned a00 = __shfl(pk00, srcA), a01 = __shfl(pk01, srcA);
            unsigned a10 = __shfl(pk10, srcA), a11 = __shfl(pk11, srcA);
            unsigned b00 = __shfl(pk00, srcB), b01 = __shfl(pk01, srcB);
            unsigned b10 = __shfl(pk10, srcB), b11 = __shfl(pk11, srcB);
            const bool hi = g >= 2;
            u32x4 pu;
            pu[0] = hi ? a10 : a00;
            pu[1] = hi ? a11 : a01;
            pu[2] = hi ? b10 : b00;
            pu[3] = hi ? b11 : b01;
            bf16x8 pf = __builtin_bit_cast(bf16x8, pu);
            #pragma unroll
            for (int dt = 0; dt < 4; ++dt) {
                const int vrow = dt * 16 + col;
                bf16x8 vf = *(const bf16x8*)(vtbuf + sb * 4096
                                + ((vrow * 64 + g * 16) ^ ((vrow & 7) << 4)));
                acc[dt] = __builtin_amdgcn_mfma_f32_16x16x32_bf16(vf, pf, acc[dt], 0, 0, 0);
            }
        }
#endif

        // ---- non-DMA paths: write next iteration into the other buffer ----
        if (t + 1 < NT) {
            const int nb = (t + 1) & 1;
            if constexpr (IMG) {
#if !HAVE_GLL
                #pragma unroll
                for (int sb = 0; sb < 2; ++sb) {
                    *(f32x4*)(kdst   + nb * 8192 + sb * 4096) = kreg[sb];
                    *(f32x4*)(vtdst0 + nb * 8192 + sb * 4096) = vreg[sb];
                }
#endif
            } else {
                #pragma unroll
                for (int sb = 0; sb < 2; ++sb) {
                    bf16x8 kb16;
                    bf16x4 vb0, vb1;
                    #pragma unroll
                    for (int b = 0; b < 4; ++b) {
                        kb16[b] = (__bf16)kr[sb][0][b]; kb16[4 + b] = (__bf16)kr[sb][1][b];
                        vb0[b] = (__bf16)vv[sb][b];     vb1[b] = (__bf16)vv[sb][4 + b];
                    }
                    *(bf16x8*)(kdst   + nb * 8192 + sb * 4096) = kb16;
                    *(bf16x4*)(vtdst0 + nb * 8192 + sb * 4096) = vb0;
                    *(bf16x4*)(vtdst1 + nb * 8192 + sb * 4096) = vb1;
                }
            }
        }
        __syncthreads();
    }

    // ---- deferred l reduction across g-groups ----
    l += __shfl_xor(l, 16);
    l += __shfl_xor(l, 32);

    // ---- merge halves (flash combine in O^T layout, base-2 domain) ----
    float* eacc = (float*)smem;            // [w4][q=col 16][d 64]
    float* eml  = (float*)(smem + 16384);  // [w4*16+col]*2

    if (half == 1) {
        #pragma unroll
        for (int dt = 0; dt < 4; ++dt)
            *(f32x4*)(eacc + w4 * 1024 + col * 64 + dt * 16 + g * 4) = acc[dt];
        if (g == 0) {
            eml[(w4 * 16 + col) * 2 + 0] = m;
            eml[(w4 * 16 + col) * 2 + 1] = l;
        }
    }
    __syncthreads();
    if (half == 0) {
        float m2 = eml[(w4 * 16 + col) * 2 + 0];
        float l2 = eml[(w4 * 16 + col) * 2 + 1];
        float mm = fmaxf(m, m2);
        float a1 = __builtin_amdgcn_exp2f(m - mm);
        float a2 = __builtin_amdgcn_exp2f(m2 - mm);
        float inv = 1.0f / (l * a1 + l2 * a2);
        float* orow = out + ((size_t)h * SEQ_LEN + qbase + col) * HEAD_DIM;
        #pragma unroll
        for (int dt = 0; dt < 4; ++dt) {
            f32x4 o2 = *(const f32x4*)(eacc + w4 * 1024 + col * 64 + dt * 16 + g * 4);
            *(f32x4*)(orow + dt * 16 + g * 4) = (acc[dt] * a1 + o2 * a2) * inv;
        }
    }
}

extern "C" void kernel_launch(void* const* d_in, const int* in_sizes, int n_in,
                              void* d_out, int out_size, void* d_ws, size_t ws_size,
                              hipStream_t stream) {
    const float* q = (const float*)d_in[0];
    const float* k = (const float*)d_in[1];
    const float* v = (const float*)d_in[2];
    float* out = (float*)d_out;

    const size_t imgBytes = (size_t)N_HEADS * NTILE_TOT * 4096;   // 4 MiB each
    const size_t need = 2 * imgBytes + N_HEADS * NTILE_TOT * sizeof(float);

    dim3 grid(SEQ_LEN / 64, N_HEADS, 1);
    if (ws_size >= need) {
        char* kimg     = (char*)d_ws;
        char* vtimg    = kimg + imgBytes;
        float* tilemax = (float*)(vtimg + imgBytes);
        prep_kernel<<<dim3(NTILE_TOT, N_HEADS, 1), dim3(256, 1, 1), 0, stream>>>(
            k, v, kimg, vtimg, tilemax);
        attn_alibi_kernel<true><<<grid, dim3(512, 1, 1), 0, stream>>>(
            q, k, v, out, kimg, vtimg, tilemax);
    } else {
        attn_alibi_kernel<false><<<grid, dim3(512, 1, 1), 0, stream>>>(
            q, k, v, out, nullptr, nullptr, nullptr);
    }
}